// Round 8
// baseline (162.991 us; speedup 1.0000x reference)
//
#include <hip/hip_runtime.h>

typedef unsigned short u16;
typedef unsigned int u32;
typedef short bf16x8 __attribute__((ext_vector_type(8)));
typedef float f32x4 __attribute__((ext_vector_type(4)));

#define NAG 32
#define STATE 512
#define EMBED 64
#define TB 128   // samples per block; grid = 256 = 1 block/CU

// d_ws bf16 layout (u16 element offsets).
#define OFF_W1L1 0
#define OFF_W2L1 32768
#define OFF_B1W  65536
#define OFF_B2L1 98304
#define OFF_W1L2 131072
#define OFF_W2L2 262144
#define WS_TOTAL 266240

__device__ __forceinline__ float bf2f(u16 u) {
    u32 i = ((u32)u) << 16; float f;
    __builtin_memcpy(&f, &i, 4); return f;
}
__device__ __forceinline__ u16 f2bf(float f) {
    u32 i; __builtin_memcpy(&i, &f, 4);
    return (u16)((i + 0x8000u) >> 16);
}
__device__ __forceinline__ bf16x8 ld8(const u16* p) {
    return *reinterpret_cast<const bf16x8*>(p);
}
__device__ __forceinline__ bf16x8 cvt8(f32x4 a, f32x4 b) {
    bf16x8 r;
#pragma unroll
    for (int i = 0; i < 4; ++i) r[i]     = (short)f2bf(a[i]);
#pragma unroll
    for (int i = 0; i < 4; ++i) r[i + 4] = (short)f2bf(b[i]);
    return r;
}
__device__ __forceinline__ void dma16(const void* g, void* l) {
    __builtin_amdgcn_global_load_lds(
        (const __attribute__((address_space(1))) u32*)g,
        (__attribute__((address_space(3))) u32*)l, 16, 0, 0);
}

__global__ __launch_bounds__(256) void cvt_weights(
    const float* __restrict__ w1l1w, const float* __restrict__ w2l1w,
    const float* __restrict__ b1w,   const float* __restrict__ b2l1w,
    const float* __restrict__ w1l2w, const float* __restrict__ w2l2w,
    u16* __restrict__ ws)
{
    int idx = blockIdx.x * 256 + threadIdx.x;
    const float* src; int off;
    if      (idx < OFF_W2L1)  { src = w1l1w; off = OFF_W1L1; }
    else if (idx < OFF_B1W)   { src = w2l1w; off = OFF_W2L1; }
    else if (idx < OFF_B2L1)  { src = b1w;   off = OFF_B1W;  }
    else if (idx < OFF_W1L2)  { src = b2l1w; off = OFF_B2L1; }
    else if (idx < OFF_W2L2)  { src = w1l2w; off = OFF_W1L2; }
    else if (idx < WS_TOTAL)  { src = w2l2w; off = OFF_W2L2; }
    else return;
    ws[idx] = f2bf(src[idx - off]);
}

__global__ __launch_bounds__(256, 1) void qmix_kernel(
    const float* __restrict__ qs,    const float* __restrict__ st,
    const u16*  __restrict__ wsb,
    const float* __restrict__ w1l1b, const float* __restrict__ w1l2b,
    const float* __restrict__ w2l1b, const float* __restrict__ w2l2b,
    const float* __restrict__ b1b,   const float* __restrict__ b2l1b,
    const float* __restrict__ b2l2w, const float* __restrict__ b2l2b,
    float* __restrict__ out)
{
    __shared__ u16  wbuf[32768];      // 64 KB staging slice; hid overlays later
    __shared__ u16  y[TB][264];       // 67.6 KB: [0:64) h1, [64:128) h2, [128:192) b1v, [192:256) hb
    __shared__ u16  qslb[TB][40];     // 10 KB agent_qs bf16
    __shared__ u16  w1bs[2048];       // 4 KB w1l2b bf16
    __shared__ float qacc[TB];
    __shared__ float b2wv[64];
    // total ~146 KB -> 1 block/CU

    const int t    = threadIdx.x;
    const int wave = t >> 6, lane = t & 63;
    const int m = lane & 15, quad = lane >> 4;
    const int sbase = blockIdx.x * TB;
    const int s0 = wave * 32;          // wave owns samples s0..s0+31 in all phases

    // ---- prologue staging: qs->bf16, w1l2b->bf16, b2w ----
    if (t < 64) b2wv[t] = b2l2w[t];
    {
        const int r = t >> 1, h = t & 1;
        const float* qp0 = qs + (size_t)(sbase + r) * NAG + h * 16;
        f32x4 q0 = *reinterpret_cast<const f32x4*>(qp0);
        f32x4 q1 = *reinterpret_cast<const f32x4*>(qp0 + 4);
        f32x4 q2 = *reinterpret_cast<const f32x4*>(qp0 + 8);
        f32x4 q3 = *reinterpret_cast<const f32x4*>(qp0 + 12);
        *reinterpret_cast<bf16x8*>(&qslb[r][h * 16])     = cvt8(q0, q1);
        *reinterpret_cast<bf16x8*>(&qslb[r][h * 16 + 8]) = cvt8(q2, q3);
        f32x4 w0 = *reinterpret_cast<const f32x4*>(w1l2b + t * 8);
        f32x4 w1 = *reinterpret_cast<const f32x4*>(w1l2b + t * 8 + 4);
        *reinterpret_cast<bf16x8*>(&w1bs[t * 8]) = cvt8(w0, w1);
    }

    // ---- Phase A biases ----
    float abias[16];
#pragma unroll
    for (int tt = 0; tt < 4; ++tt) abias[tt]      = w1l1b[tt * 16 + m];
#pragma unroll
    for (int tt = 0; tt < 4; ++tt) abias[tt + 4]  = w2l1b[tt * 16 + m];
#pragma unroll
    for (int tt = 0; tt < 4; ++tt) abias[tt + 8]  = b1b[tt * 16 + m];
#pragma unroll
    for (int tt = 0; tt < 4; ++tt) abias[tt + 12] = b2l1b[tt * 16 + m];

    // ---- Phase A: Y[128][256] = states @ WA^T; wave = 32 samples x 256 feats ----
    // 4 K-slices of 128. wbuf as [256 rows][128 u16], 16 chunks of 8 u16, XOR-16 swizzle.
    const float* sp0 = st + (size_t)(sbase + s0 + m) * STATE;
    const int r4 = lane >> 4, c16 = lane & 15;   // Phase-A staging: 4 rows/dma, 16 chunks
    const int r8 = lane >> 3, c8 = lane & 7;     // Phase-B staging: 8 rows/dma, 8 chunks

    f32x4 acc0[16] = {}, acc1[16] = {};
    for (int ksl = 0; ksl < 4; ++ksl) {
        __syncthreads();   // previous slice consumed (also covers prologue LDS)
#pragma unroll
        for (int j = 0; j < 16; ++j) {
            const int row = wave * 64 + j * 4 + r4;
            const int sc  = c16 ^ (row & 15);
            dma16(wsb + (size_t)row * STATE + ksl * 128 + sc * 8,
                  &wbuf[(wave * 64 + j * 4) * 128 + lane * 8]);
        }
        // per-lane state fragments for this slice (2 groups x 4 k-steps x 2)
        f32x4 av[2][4][2];
#pragma unroll
        for (int g = 0; g < 2; ++g)
#pragma unroll
            for (int ks = 0; ks < 4; ++ks) {
                const float* p = sp0 + g * 16 * STATE + ksl * 128 + ks * 32 + quad * 8;
                av[g][ks][0] = *reinterpret_cast<const f32x4*>(p);
                av[g][ks][1] = *reinterpret_cast<const f32x4*>(p + 4);
            }
        __builtin_amdgcn_s_waitcnt(0);
        __syncthreads();
#pragma unroll
        for (int ks = 0; ks < 4; ++ks) {
            bf16x8 af0 = cvt8(av[0][ks][0], av[0][ks][1]);
            bf16x8 af1 = cvt8(av[1][ks][0], av[1][ks][1]);
#pragma unroll
            for (int tt = 0; tt < 16; ++tt) {
                const int row = tt * 16 + m;
                const int lc = (ks * 4 + quad) ^ (row & 15);
                bf16x8 b = ld8(&wbuf[row * 128 + lc * 8]);
                acc0[tt] = __builtin_amdgcn_mfma_f32_16x16x32_bf16(af0, b, acc0[tt], 0, 0, 0);
                acc1[tt] = __builtin_amdgcn_mfma_f32_16x16x32_bf16(af1, b, acc1[tt], 0, 0, 0);
            }
        }
    }
#pragma unroll
    for (int tt = 0; tt < 16; ++tt) {
        const bool isrelu = (tt < 8) || (tt >= 12);   // tiles 8..11 = b1v (linear)
        const int fcol = tt * 16 + m;
#pragma unroll
        for (int r = 0; r < 4; ++r) {
            float v0 = acc0[tt][r] + abias[tt];
            float v1 = acc1[tt][r] + abias[tt];
            if (isrelu) { v0 = fmaxf(v0, 0.f); v1 = fmaxf(v1, 0.f); }
            y[s0 + quad * 4 + r][fcol]      = f2bf(v0);
            y[s0 + 16 + quad * 4 + r][fcol] = f2bf(v1);
        }
    }
    __syncthreads();

    // ---- Phase B: hidden = elu(sum_a qs[s,a]*|h1 @ W1l2[a]^T + b| + b1v) ----
    bf16x8 haf[2][2];
#pragma unroll
    for (int g = 0; g < 2; ++g) {
        haf[g][0] = *reinterpret_cast<const bf16x8*>(&y[s0 + g * 16 + m][quad * 8]);
        haf[g][1] = *reinterpret_cast<const bf16x8*>(&y[s0 + g * 16 + m][32 + quad * 8]);
    }

    f32x4 hacc[2][4] = {};
    for (int bs = 0; bs < 4; ++bs) {
        __syncthreads();   // previous slice consumed
        // stage 8 agents = 512 rows x 64 u16 (64 KB); wave stages rows wave*128..+127
#pragma unroll
        for (int j = 0; j < 16; ++j) {
            const int row = wave * 128 + j * 8 + r8;   // local row in slice
            const int sc  = c8 ^ (row & 7);
            dma16(wsb + OFF_W1L2 + ((size_t)bs * 512 + row) * EMBED + sc * 8,
                  &wbuf[(wave * 128 + j * 8) * 64 + lane * 8]);
        }
        // qs for this slice's 8 agents
        bf16x8 qv8[2][4];
#pragma unroll
        for (int g = 0; g < 2; ++g)
#pragma unroll
            for (int r = 0; r < 4; ++r)
                qv8[g][r] = *reinterpret_cast<const bf16x8*>(&qslb[s0 + g * 16 + quad * 4 + r][bs * 8]);
        __builtin_amdgcn_s_waitcnt(0);
        __syncthreads();
#pragma unroll
        for (int aloc = 0; aloc < 8; ++aloc) {
#pragma unroll
            for (int tp = 0; tp < 4; ++tp) {
                const int row = aloc * 64 + tp * 16 + m;
                bf16x8 b0 = ld8(&wbuf[row * 64 + ((quad) ^ (row & 7)) * 8]);
                bf16x8 b1 = ld8(&wbuf[row * 64 + ((4 + quad) ^ (row & 7)) * 8]);
                const float bias = bf2f(w1bs[(bs * 8 + aloc) * EMBED + tp * 16 + m]);
#pragma unroll
                for (int g = 0; g < 2; ++g) {
                    f32x4 p = {};
                    p = __builtin_amdgcn_mfma_f32_16x16x32_bf16(haf[g][0], b0, p, 0, 0, 0);
                    p = __builtin_amdgcn_mfma_f32_16x16x32_bf16(haf[g][1], b1, p, 0, 0, 0);
#pragma unroll
                    for (int r = 0; r < 4; ++r)
                        hacc[g][tp][r] += bf2f((u16)qv8[g][r][aloc]) * fabsf(p[r] + bias);
                }
            }
        }
    }
    __syncthreads();   // all waves done with wbuf -> overlay hid
    u16* hid = wbuf;   // [128][66]
#pragma unroll
    for (int g = 0; g < 2; ++g)
#pragma unroll
        for (int tp = 0; tp < 4; ++tp)
#pragma unroll
            for (int r = 0; r < 4; ++r) {
                const int s = s0 + g * 16 + quad * 4 + r, e = tp * 16 + m;
                float v = hacc[g][tp][r] + bf2f(y[s][128 + e]);
                v = (v > 0.f) ? v : (__expf(v) - 1.f);
                hid[s * 66 + e] = f2bf(v);
            }
    __syncthreads();

    // ---- Phase C: w2 = |h2 @ W2l2^T + b|; q = sum_e hidden*w2 (wave-local) ----
    bf16x8 h2f[2][2];
#pragma unroll
    for (int g = 0; g < 2; ++g) {
        h2f[g][0] = *reinterpret_cast<const bf16x8*>(&y[s0 + g * 16 + m][64 + quad * 8]);
        h2f[g][1] = *reinterpret_cast<const bf16x8*>(&y[s0 + g * 16 + m][96 + quad * 8]);
    }

    f32x4 qp[2] = {};
#pragma unroll
    for (int tp = 0; tp < 4; ++tp) {
        const u16* wc = wsb + OFF_W2L2 + (size_t)(tp * 16 + m) * EMBED + quad * 8;
        bf16x8 b0 = ld8(wc);
        bf16x8 b1 = ld8(wc + 32);
        const float bias = w2l2b[tp * 16 + m];
#pragma unroll
        for (int g = 0; g < 2; ++g) {
            f32x4 p = {};
            p = __builtin_amdgcn_mfma_f32_16x16x32_bf16(h2f[g][0], b0, p, 0, 0, 0);
            p = __builtin_amdgcn_mfma_f32_16x16x32_bf16(h2f[g][1], b1, p, 0, 0, 0);
#pragma unroll
            for (int r = 0; r < 4; ++r)
                qp[g][r] += bf2f(hid[(s0 + g * 16 + quad * 4 + r) * 66 + tp * 16 + m])
                            * fabsf(p[r] + bias);
        }
    }
#pragma unroll
    for (int off = 1; off < 16; off <<= 1) {
#pragma unroll
        for (int g = 0; g < 2; ++g)
#pragma unroll
            for (int r = 0; r < 4; ++r) qp[g][r] += __shfl_xor(qp[g][r], off, 64);
    }
    if (m == 0) {
#pragma unroll
        for (int g = 0; g < 2; ++g)
#pragma unroll
            for (int r = 0; r < 4; ++r) qacc[s0 + g * 16 + quad * 4 + r] = qp[g][r];
    }
    __syncthreads();

    // ---- Phase D: b2 + final sum (LDS-only) ----
    if (t < TB) {
        float q = qacc[t] + b2l2b[0];
        float acc2 = 0.f;
#pragma unroll
        for (int kk = 0; kk < 8; ++kk) {
            bf16x8 hv = *reinterpret_cast<const bf16x8*>(&y[t][192 + kk * 8]);
#pragma unroll
            for (int j = 0; j < 8; ++j)
                acc2 += bf2f((u16)hv[j]) * b2wv[kk * 8 + j];
        }
        out[sbase + t] = q + acc2;
    }
}

extern "C" void kernel_launch(void* const* d_in, const int* in_sizes, int n_in,
                              void* d_out, int out_size, void* d_ws, size_t ws_size,
                              hipStream_t stream)
{
    const float* qs    = (const float*)d_in[0];
    const float* st    = (const float*)d_in[1];
    const float* w1l1w = (const float*)d_in[2];
    const float* w1l1b = (const float*)d_in[3];
    const float* w1l2w = (const float*)d_in[4];
    const float* w1l2b = (const float*)d_in[5];
    const float* w2l1w = (const float*)d_in[6];
    const float* w2l1b = (const float*)d_in[7];
    const float* w2l2w = (const float*)d_in[8];
    const float* w2l2b = (const float*)d_in[9];
    const float* b1w   = (const float*)d_in[10];
    const float* b1b   = (const float*)d_in[11];
    const float* b2l1w = (const float*)d_in[12];
    const float* b2l1b = (const float*)d_in[13];
    const float* b2l2w = (const float*)d_in[14];
    const float* b2l2b = (const float*)d_in[15];

    u16* wsb = (u16*)d_ws;

    cvt_weights<<<(WS_TOTAL + 255) / 256, 256, 0, stream>>>(
        w1l1w, w2l1w, b1w, b2l1w, w1l2w, w2l2w, wsb);

    int B = in_sizes[0] / NAG;        // 32768
    int grid = B / TB;                // 256 = 1 block/CU
    qmix_kernel<<<grid, 256, 0, stream>>>(
        qs, st, wsb,
        w1l1b, w1l2b, w2l1b, w2l2b, b1b, b2l1b, b2l2w, b2l2b,
        (float*)d_out);
}